// Round 1
// baseline (637.173 us; speedup 1.0000x reference)
//
#include <hip/hip_runtime.h>

// Problem constants (from reference setup_inputs)
#define B_   8
#define CIN  64
#define CM   16      // compressed channels
#define H_   192
#define W_   384
#define ND   41      // MAX_DISP+1
#define SLOPE 0.1f
#define HW   (H_ * W_)
#define MINI (B_ * CM * HW)   // elements per compressed tensor = 9,437,184

// ---------------------------------------------------------------------------
// Kernel 1: 3x3 conv (64->16, pad 1) + bias + LeakyReLU(0.1), both tensors.
// Each thread: 4 consecutive x pixels, all 16 output channels (64 accs).
// Weights read with wave-uniform indices from const __restrict__ -> s_load.
// ---------------------------------------------------------------------------
__global__ __launch_bounds__(256) void conv3x3_leaky(
    const float* __restrict__ ina, const float* __restrict__ inb,
    const float* __restrict__ wt,   // [16][64][3][3] OIHW
    const float* __restrict__ bias, // [16]
    float* __restrict__ mini)       // [2][B][16][H][W]
{
    int g  = blockIdx.x * 256 + threadIdx.x;      // 294,912 total, exact
    int xg = (g % (W_ / 4)) * 4;
    int r  = g / (W_ / 4);
    int y  = r % H_;  r /= H_;
    int b  = r % B_;  r /= B_;
    int t  = r;                                   // 0 = a, 1 = b tensor
    const float* src = t ? inb : ina;

    float acc[CM][4];
    #pragma unroll
    for (int co = 0; co < CM; ++co) {
        float bv = bias[co];
        acc[co][0] = bv; acc[co][1] = bv; acc[co][2] = bv; acc[co][3] = bv;
    }

    #pragma unroll 1
    for (int c = 0; c < CIN; ++c) {
        const float* chan = src + (size_t)(b * CIN + c) * HW;
        #pragma unroll
        for (int dy = 0; dy < 3; ++dy) {
            int yy = y + dy - 1;
            float w6[6];
            if (yy >= 0 && yy < H_) {
                const float* row = chan + yy * W_ + xg;
                float4 v = *(const float4*)row;
                w6[0] = (xg > 0)        ? row[-1] : 0.f;
                w6[1] = v.x; w6[2] = v.y; w6[3] = v.z; w6[4] = v.w;
                w6[5] = (xg + 4 < W_)   ? row[4]  : 0.f;
            } else {
                w6[0] = w6[1] = w6[2] = w6[3] = w6[4] = w6[5] = 0.f;
            }
            #pragma unroll
            for (int dx = 0; dx < 3; ++dx) {
                #pragma unroll
                for (int co = 0; co < CM; ++co) {
                    float wv = wt[((co * CIN + c) * 3 + dy) * 3 + dx]; // uniform
                    #pragma unroll
                    for (int p = 0; p < 4; ++p)
                        acc[co][p] += w6[p + dx] * wv;
                }
            }
        }
    }

    float* dstbase = mini + (size_t)t * MINI + ((size_t)(b * CM) * H_ + y) * W_ + xg;
    #pragma unroll
    for (int co = 0; co < CM; ++co) {
        float4 o;
        float v0 = acc[co][0], v1 = acc[co][1], v2 = acc[co][2], v3 = acc[co][3];
        o.x = v0 >= 0.f ? v0 : SLOPE * v0;
        o.y = v1 >= 0.f ? v1 : SLOPE * v1;
        o.z = v2 >= 0.f ? v2 : SLOPE * v2;
        o.w = v3 >= 0.f ? v3 : SLOPE * v3;
        *(float4*)(dstbase + (size_t)co * HW) = o;
    }
}

// ---------------------------------------------------------------------------
// Kernel 2: 1-D correlation, 41 displacements, mean over 16 channels.
// One block per (b, y) row; b-row staged in LDS as [x][c] stride 20
// (16B-aligned float4 reads, conflict-free); a-vector in registers.
// ---------------------------------------------------------------------------
#define LSTRIDE 20
__global__ __launch_bounds__(384) void corr1d_kernel(
    const float* __restrict__ mini, float* __restrict__ out)
{
    int b = blockIdx.x / H_;
    int y = blockIdx.x % H_;
    __shared__ __align__(16) float bl[W_ * LSTRIDE];   // 30,720 B

    int tid = threadIdx.x;
    const float* bbase = mini + (size_t)MINI + ((size_t)(b * CM) * H_ + y) * W_;
    #pragma unroll
    for (int i = tid; i < W_ * CM; i += 384) {
        int c = i / W_;
        int x = i - c * W_;
        bl[x * LSTRIDE + c] = bbase[(size_t)c * HW + x];   // coalesced read
    }
    __syncthreads();

    int x = tid;   // 0..383
    const float* abase = mini + ((size_t)(b * CM) * H_ + y) * W_ + x;
    float av[CM];
    #pragma unroll
    for (int c = 0; c < CM; ++c) av[c] = abase[(size_t)c * HW]; // coalesced

    float* obase = out + ((size_t)(b * ND) * H_ + y) * W_ + x;
    #pragma unroll 1
    for (int d = 0; d < ND; ++d) {
        float s = 0.f;
        int xs = x - d;
        if (xs >= 0) {
            const float4* bv = (const float4*)(bl + xs * LSTRIDE);
            float4 b0 = bv[0], b1 = bv[1], b2 = bv[2], b3 = bv[3];
            s  = av[0]  * b0.x + av[1]  * b0.y + av[2]  * b0.z + av[3]  * b0.w;
            s += av[4]  * b1.x + av[5]  * b1.y + av[6]  * b1.z + av[7]  * b1.w;
            s += av[8]  * b2.x + av[9]  * b2.y + av[10] * b2.z + av[11] * b2.w;
            s += av[12] * b3.x + av[13] * b3.y + av[14] * b3.z + av[15] * b3.w;
        }
        obase[(size_t)d * HW] = s * (1.0f / 16.0f);
    }
}

// ---------------------------------------------------------------------------
extern "C" void kernel_launch(void* const* d_in, const int* in_sizes, int n_in,
                              void* d_out, int out_size, void* d_ws, size_t ws_size,
                              hipStream_t stream) {
    const float* conv1a = (const float*)d_in[0];
    const float* conv1b = (const float*)d_in[1];
    const float* W_comp = (const float*)d_in[2];
    const float* b_comp = (const float*)d_in[3];
    float* out = (float*)d_out;
    float* ws  = (float*)d_ws;    // needs 2*MINI*4 = 75.5 MB scratch

    int conv_blocks = (2 * B_ * H_ * (W_ / 4)) / 256;   // 1152
    conv3x3_leaky<<<conv_blocks, 256, 0, stream>>>(conv1a, conv1b, W_comp, b_comp, ws);

    corr1d_kernel<<<B_ * H_, 384, 0, stream>>>(ws, out);
}

// Round 2
// 437.943 us; speedup vs baseline: 1.4549x; 1.4549x over previous
//
#include <hip/hip_runtime.h>
#include <hip/hip_bf16.h>

// Problem constants
#define B_   8
#define CIN  64
#define CM   16      // compressed channels
#define H_   192
#define W_   384
#define ND   41      // MAX_DISP+1
#define HW   (H_ * W_)
#define SLOPE 0.1f
#define SMINI ((size_t)B_ * CM * H_ * W_)   // elems per compressed tensor

typedef __attribute__((ext_vector_type(8))) short short8v;   // 8 bf16 = 1 MFMA frag
typedef __attribute__((ext_vector_type(4))) float floatx4;

__device__ __forceinline__ float bf2f(short h) {
    union { unsigned u; float f; } cv;
    cv.u = ((unsigned)(unsigned short)h) << 16;
    return cv.f;
}
__device__ __forceinline__ short f2bf(float f) {
    __hip_bfloat16 h = __float2bfloat16(f);   // RNE
    return *(short*)&h;
}

// ---------------------------------------------------------------------------
// Kernel 0: reorder weights OIHW fp32 -> [co][k] bf16 with k = (dy*3+dx)*64 + c
// ---------------------------------------------------------------------------
__global__ void wprep_kernel(const float* __restrict__ w, short* __restrict__ wbf) {
    int i = blockIdx.x * 256 + threadIdx.x;
    if (i >= CM * 576) return;
    int co = i / 576, k = i - co * 576;
    int t = k >> 6, c = k & 63;               // k = t*64 + c
    wbf[i] = f2bf(w[(co * CIN + c) * 9 + t]); // w[co][c][dy][dx], t = dy*3+dx
}

// ---------------------------------------------------------------------------
// Kernel 1: 3x3 conv 64->16 + bias + LeakyReLU via MFMA implicit GEMM.
// Block: 6x32 output pixels of one (tensor,b). LDS: 8x34 input sites x 64c bf16
// [site][c] stride 72 (2-way bank alias = free). A-operand = weights (16 co as
// M), B-operand = pixels (N). D lane layout -> contiguous [pixel][co] bf16 NHWC
// stores, 8 B/lane fully coalesced.
// ---------------------------------------------------------------------------
#define YT 6
#define XT 32
#define LC 34
#define PSTR 72

__global__ __launch_bounds__(256, 4) void conv_mfma(
    const float* __restrict__ ina, const float* __restrict__ inb,
    const short* __restrict__ wbf, const float* __restrict__ bias,
    short* __restrict__ mini)      // [2][B][H][W][16] bf16
{
    __shared__ __align__(16) short px[8 * LC * PSTR];   // 39,168 B

    int blk = blockIdx.x;
    int xt = blk % 12;  blk /= 12;
    int yt = blk % 32;  blk /= 32;
    int b  = blk & 7;
    int t  = blk >> 3;
    const float* src = t ? inb : ina;
    int x0 = xt * XT, y0 = yt * YT;
    int tid = threadIdx.x;

    // ---- stage input patch rows y0-1..y0+6, cols x0-1..x0+32, all 64 c ----
    // e indexes (row, c-quad, lx): 8*16*34 = 4352 = 17*256
    #pragma unroll
    for (int i = 0; i < 17; ++i) {
        int e = i * 256 + tid;
        int lx = e % LC;
        int rcq = e / LC;          // 0..127
        int row = rcq >> 4;        // 0..7
        int c0 = (rcq & 15) << 2;  // 0,4,..,60
        int gy = y0 - 1 + row;
        int gx = x0 - 1 + lx;
        float v0 = 0.f, v1 = 0.f, v2 = 0.f, v3 = 0.f;
        if ((unsigned)gy < (unsigned)H_ && (unsigned)gx < (unsigned)W_) {
            const float* p = src + ((size_t)(b * CIN + c0)) * HW + (size_t)gy * W_ + gx;
            v0 = p[0]; v1 = p[HW]; v2 = p[2 * HW]; v3 = p[3 * HW];
        }
        short4 q;
        q.x = f2bf(v0); q.y = f2bf(v1); q.z = f2bf(v2); q.w = f2bf(v3);
        *(short4*)(px + (row * LC + lx) * PSTR + c0) = q;   // 8 B, aligned
    }

    int lane = tid & 63;
    int n16  = lane & 15;    // A: co row group ; B/D: pixel within tile
    int quad = lane >> 4;

    // ---- preload weight A-frags for all 18 K-steps (L1/L2-hot, 18 KB) ----
    short8v af[18];
    #pragma unroll
    for (int ks = 0; ks < 18; ++ks)
        af[ks] = *(const short8v*)(wbf + n16 * 576 + ks * 32 + quad * 8);

    __syncthreads();

    // ---- MFMA main loop: 3 M-tiles per wave, 18 K-steps ----
    int wv = tid >> 6;
    floatx4 acc[3] = {{0,0,0,0},{0,0,0,0},{0,0,0,0}};
    int base[3];
    #pragma unroll
    for (int j = 0; j < 3; ++j) {
        int mt = wv * 3 + j;                 // 0..11
        int r = mt >> 1, xb = (mt & 1) << 4; // output row 0..5, x-base 0/16
        // LDS site for (r+dy, xb+n16+dx) handled via per-ks immediate offset
        base[j] = (r * LC + xb + n16) * PSTR + quad * 8;
    }
    #pragma unroll
    for (int ks = 0; ks < 18; ++ks) {
        const int tap = ks >> 1, ch = ks & 1;
        const int dy = tap / 3, dx = tap % 3;
        const int off = (dy * LC + dx) * PSTR + ch * 32;   // compile-time
        #pragma unroll
        for (int j = 0; j < 3; ++j) {
            short8v bfr = *(const short8v*)(px + base[j] + off);
            acc[j] = __builtin_amdgcn_mfma_f32_16x16x32_bf16(af[ks], bfr, acc[j], 0, 0, 0);
        }
    }

    // ---- epilogue: bias + LeakyReLU, bf16 NHWC store (8 B/lane coalesced) ----
    float bia[4];
    #pragma unroll
    for (int i = 0; i < 4; ++i) bia[i] = bias[quad * 4 + i];
    #pragma unroll
    for (int j = 0; j < 3; ++j) {
        int mt = wv * 3 + j;
        int r = mt >> 1, xb = (mt & 1) << 4;
        int y = y0 + r, x = x0 + xb + n16;
        size_t o = (((size_t)(t * B_ + b) * H_ + y) * W_ + x) * CM + quad * 4;
        short4 q;
        float v;
        v = acc[j][0] + bia[0]; v = v >= 0.f ? v : SLOPE * v; q.x = f2bf(v);
        v = acc[j][1] + bia[1]; v = v >= 0.f ? v : SLOPE * v; q.y = f2bf(v);
        v = acc[j][2] + bia[2]; v = v >= 0.f ? v : SLOPE * v; q.z = f2bf(v);
        v = acc[j][3] + bia[3]; v = v >= 0.f ? v : SLOPE * v; q.w = f2bf(v);
        *(short4*)(mini + o) = q;
    }
}

// ---------------------------------------------------------------------------
// Kernel 2: 41-disparity correlation over NHWC bf16 mini. One block per (b,y).
// b-row staged in LDS at 48 B/pixel stride (16 B aligned, 2-way alias = free).
// ---------------------------------------------------------------------------
#define BSTR 24   // shorts per pixel in LDS (16 data + 8 pad)

__global__ __launch_bounds__(384) void corr_nhwc(
    const short* __restrict__ mini, float* __restrict__ out)
{
    __shared__ __align__(16) short bl[W_ * BSTR];   // 18,432 B
    int b = blockIdx.x / H_;
    int y = blockIdx.x % H_;
    int x = threadIdx.x;   // 0..383

    size_t arow = ((size_t)b * H_ + y) * W_ * CM;          // tensor 0
    size_t brow = ((size_t)(B_ + b) * H_ + y) * W_ * CM;   // tensor 1

    short8v p0 = *(const short8v*)(mini + brow + (size_t)x * CM);
    short8v p1 = *(const short8v*)(mini + brow + (size_t)x * CM + 8);
    *(short8v*)(bl + x * BSTR) = p0;
    *(short8v*)(bl + x * BSTR + 8) = p1;

    float av[16];
    short8v a0 = *(const short8v*)(mini + arow + (size_t)x * CM);
    short8v a1 = *(const short8v*)(mini + arow + (size_t)x * CM + 8);
    #pragma unroll
    for (int i = 0; i < 8; ++i) { av[i] = bf2f(a0[i]); av[8 + i] = bf2f(a1[i]); }

    __syncthreads();

    float* ob = out + ((size_t)b * ND * H_ + y) * W_ + x;
    #pragma unroll 1
    for (int d = 0; d < ND; ++d) {
        float s = 0.f;
        int xs = x - d;
        if (xs >= 0) {
            const short* bp = bl + xs * BSTR;
            short8v c0 = *(const short8v*)bp;
            short8v c1 = *(const short8v*)(bp + 8);
            float s0 = 0.f, s1 = 0.f;
            #pragma unroll
            for (int i = 0; i < 8; ++i) {
                s0 += av[i]     * bf2f(c0[i]);
                s1 += av[8 + i] * bf2f(c1[i]);
            }
            s = s0 + s1;
        }
        ob[(size_t)d * HW] = s * 0.0625f;
    }
}

// ---------------------------------------------------------------------------
extern "C" void kernel_launch(void* const* d_in, const int* in_sizes, int n_in,
                              void* d_out, int out_size, void* d_ws, size_t ws_size,
                              hipStream_t stream) {
    const float* conv1a = (const float*)d_in[0];
    const float* conv1b = (const float*)d_in[1];
    const float* W_comp = (const float*)d_in[2];
    const float* b_comp = (const float*)d_in[3];
    float* out = (float*)d_out;

    short* mini = (short*)d_ws;            // 2*SMINI bf16 = 37.7 MB
    short* wbf  = mini + 2 * SMINI;        // 16x576 bf16

    wprep_kernel<<<36, 256, 0, stream>>>(W_comp, wbf);
    conv_mfma<<<2 * B_ * 32 * 12, 256, 0, stream>>>(conv1a, conv1b, wbf, b_comp, mini);
    corr_nhwc<<<B_ * H_, 384, 0, stream>>>(mini, out);
}